// Round 10
// baseline (4964.160 us; speedup 1.0000x reference)
//
#include <hip/hip_runtime.h>
#include <math.h>

#define TT 2048
#define NB 64
#define EE 256
#define HH 256
#define PJ 16    // j-partitions recorded in part[] (unchanged layout)
#define XLD 288  // swizzled row: 256 + 4 pad per 32 floats
#define RS1 280  // red_s kc stride
#define RS2 72   // red_s batch stride
#define RBOFF (8 * RS1)   // context-B offset within red_s

typedef float f32x4 __attribute__((ext_vector_type(4)));

__device__ __forceinline__ float sigf(float x) { return 1.f / (1.f + expf(-x)); }

__device__ __forceinline__ unsigned long long packh(unsigned tag, float v) {
    union { float f; unsigned u; } c; c.f = v;
    return ((unsigned long long)tag << 32) | (unsigned long long)c.u;
}

// R15: R14 dual-context stagger + three critical-path cuts:
//  1. Tag loads PRE-ISSUED (A at loop top under phase1_A; B post-A-check
//     under phase2_A+phase1_B). Stagger guarantees the published data is
//     ~a half/step old -> pre-issued values are final, no staleness. Tag
//     loads are oldest in flight so their waitcnt never drains staging.
//  2. red_s transposed to [k2][b][jj*4+g]: epilogue reduce = 8 ds_read_b128
//     (was 32 ds_read_b32); writer +1 scalar write. k2-ascending summation
//     preserved -> bitwise identical.
//  3. Duty rebalance: A-spin={2,3,4,5}, B-spin={4,5,6,7}; A-stage wv0,1
//     (epilogue waves, never poll; loop-top issue), B-stage wv2,3 (issue
//     post-A-check). No wave carries double-spin + staging.
// All fp op orders / transported bits identical to R14 (absmax 0).
__global__ __launch_bounds__(512, 2)
void lstm_kernel(const int* __restrict__ sent, const float* __restrict__ emb,
                 const float* __restrict__ W_ih, const float* __restrict__ W_hh,
                 const float* __restrict__ b_ih, const float* __restrict__ b_hh,
                 const float* __restrict__ W_z,
                 unsigned long long* __restrict__ hbuf,
                 float* __restrict__ part)
{
    __shared__ __align__(16) float x_sw[4 * XLD];   // rows 0-1: A, 2-3: B
    __shared__ __align__(16) float h_sw[4 * XLD];
    __shared__ __align__(16) float red_s[2 * 8 * RS1];
    __shared__ __align__(16) float p_s[64];         // 0-31: A, 32-63: B
    extern __shared__ float dyn_pad[];              // occupancy pad

    const int tid  = threadIdx.x;
    if (tid == 0 && sent[0] < 0) ((volatile float*)dyn_pad)[0] = 0.f;

    // XCD-clustering swizzle (heuristic)
    const int xcd  = blockIdx.x & 7;
    const int slot = blockIdx.x >> 3;        // 0..31
    const int psys = xcd * 2 + (slot >> 4);  // 0..15 pair-system
    const int js   = slot & 15;              // j-slice
    const int bA0  = psys * 2;
    const int bB0  = 32 + psys * 2;
    const int j0   = js * 16;

    const int wv    = tid >> 6;              // 0..7
    const int lane  = tid & 63;
    const int bp    = wv & 1;                // batch within context
    const int kc    = (wv >> 1) * 2 + (lane & 1);  // 0..7 k-chunk
    const int rg    = lane >> 1;             // 0..31 row-group (2 rows)
    const int kbase = kc << 5;

    // ---- weights -> VGPRs (shared by both contexts): 128 VGPRs ----
    float4 wih_r[16], whh_r[16];
    #pragma unroll
    for (int i = 0; i < 2; ++i) {
        int lr = rg * 2 + i;
        long grow = (long)((lr >> 4) * HH + j0 + (lr & 15));
        const float4* wi = (const float4*)(W_ih + grow * EE + kbase);
        const float4* wh = (const float4*)(W_hh + grow * EE + kbase);
        #pragma unroll
        for (int mi = 0; mi < 8; ++mi) {
            wih_r[i * 8 + mi] = wi[mi];
            whh_r[i * 8 + mi] = wh[mi];
        }
    }

    // writer position in transposed red_s: row lr=rg*2 -> (lr&15)*4+(lr>>4)
    const int p0 = ((rg * 2) & 15) * 4 + ((rg * 2) >> 4);   // second row at p0+4

    // ---- epilogue state: wv0 -> A, wv1 -> B (lanes 0..31) ----
    const int eb  = (lane >> 4) & 1;  // batch 0..1 within context
    const int ejj = lane & 15;
    float bias_g[4]; float wz_r = 0.f; float c_reg = 0.f;
    if (wv < 2) {
        #pragma unroll
        for (int g = 0; g < 4; ++g)
            bias_g[g] = b_ih[g * HH + j0 + ejj] + b_hh[g * HH + j0 + ejj];
        wz_r = W_z[j0 + ejj];
    }

    // ---- spin mappings (2 tagged words per thread) ----
    const bool inA = (wv >= 2 && wv <= 5);
    const bool inB = (wv >= 4);
    const int aidx = (((wv - 2) & 3) << 6) + lane;   // 0..255 (valid if inA)
    const int bidx = (((wv - 4) & 3) << 6) + lane;   // 0..255 (valid if inB)
    const int acb = aidx >> 7, acw = (aidx & 127) << 1;
    const int bcb = bidx >> 7, bcw = (bidx & 127) << 1;
    const int acph = acw + ((acw >> 5) << 2);
    const int bcph = bcw + ((bcw >> 5) << 2);

    // ---- staging: wv0,1 -> A rows 0,1 ; wv2,3 -> B rows 2,3 ----
    const int sphys = 4 * lane + ((lane >> 3) << 2);
    int tok_st = 0;

    if (wv < 4) {   // prologue: stage x(0) for both contexts
        int base = (wv < 2) ? bA0 : bB0;
        int tk0 = sent[0 * NB + base + bp];
        f32x4 xv0 = ((const f32x4*)(emb + (long)tk0 * EE))[lane];
        *(f32x4*)(&x_sw[wv * XLD + sphys]) = xv0;
        tok_st = sent[1 * NB + base + bp];
    }
    __syncthreads();

    for (int t = 0; t < TT; ++t) {
        const bool pf = (t + 1 < TT);
        const size_t parIn  = (size_t)(((t - 1) & 1) * NB);
        const size_t parOut = (size_t)((t & 1) * NB);
        const unsigned want = (unsigned)t;

        // ---- loop-top issues ----
        f32x4 xst;
        if (pf && wv < 2) {       // A-stage issue (wv0,1 never poll)
            xst = ((const f32x4*)(emb + (long)tok_st * EE))[lane];
            if (t + 2 < TT) tok_st = sent[(t + 2) * NB + bA0 + bp];
        }
        unsigned long long a0 = 0, a1 = 0, b0v = 0, b1v = 0;
        unsigned long long* hpA = hbuf + (parIn + bA0 + acb) * HH + acw;
        unsigned long long* hpB = hbuf + (parIn + bB0 + bcb) * HH + bcw;
        if (t > 0 && inA) {       // A-tag pre-issue (hidden under phase1_A)
            a0 = __hip_atomic_load(hpA + 0, __ATOMIC_RELAXED, __HIP_MEMORY_SCOPE_AGENT);
            a1 = __hip_atomic_load(hpA + 1, __ATOMIC_RELAXED, __HIP_MEMORY_SCOPE_AGENT);
        }
        if (t > 0 && wv >= 6) {   // B-tag pre-issue for B-only spinners
            b0v = __hip_atomic_load(hpB + 0, __ATOMIC_RELAXED, __HIP_MEMORY_SCOPE_AGENT);
            b1v = __hip_atomic_load(hpB + 1, __ATOMIC_RELAXED, __HIP_MEMORY_SCOPE_AGENT);
        }

        // ================= A half =================
        float4 acc[2];
        acc[0] = make_float4(0.f, 0.f, 0.f, 0.f);
        acc[1] = make_float4(0.f, 0.f, 0.f, 0.f);
        {   // phase 1: x partials
            const float* xb = &x_sw[bp * XLD + kc * 36];
            #pragma unroll
            for (int mi = 0; mi < 8; ++mi) {
                float4 xv4 = *(const float4*)(xb + mi * 4);
                #pragma unroll
                for (int i = 0; i < 2; ++i) {
                    float4 w = wih_r[i * 8 + mi];
                    acc[i].x += w.x * xv4.x; acc[i].y += w.y * xv4.y;
                    acc[i].z += w.z * xv4.z; acc[i].w += w.w * xv4.w;
                }
            }
        }
        if (t > 0 && inA) {   // A-check (loads already in flight)
            while ((unsigned)(a0 >> 32) != want)
                a0 = __hip_atomic_load(hpA + 0, __ATOMIC_RELAXED, __HIP_MEMORY_SCOPE_AGENT);
            while ((unsigned)(a1 >> 32) != want)
                a1 = __hip_atomic_load(hpA + 1, __ATOMIC_RELAXED, __HIP_MEMORY_SCOPE_AGENT);
            union { unsigned u; float f; } c0, c1;
            c0.u = (unsigned)a0; c1.u = (unsigned)a1;
            *(float2*)(&h_sw[acb * XLD + acph]) = make_float2(c0.f, c1.f);
        }
        if (pf && (wv == 2 || wv == 3)) {   // B-stage issue (post-A-check)
            xst = ((const f32x4*)(emb + (long)tok_st * EE))[lane];
            if (t + 2 < TT) tok_st = sent[(t + 2) * NB + bB0 + bp];
        }
        if (t > 0 && (wv == 4 || wv == 5)) {   // B-tag pre-issue (post-A-check)
            b0v = __hip_atomic_load(hpB + 0, __ATOMIC_RELAXED, __HIP_MEMORY_SCOPE_AGENT);
            b1v = __hip_atomic_load(hpB + 1, __ATOMIC_RELAXED, __HIP_MEMORY_SCOPE_AGENT);
        }
        __syncthreads();   // B1a: h_A ready; x_A(t) reads done

        if (t > 0 && wv == 2 && lane < 2) {   // part A(t-1)
            float s = 0.f;
            #pragma unroll
            for (int jj = 0; jj < 16; ++jj) s += p_s[lane * 16 + jj];
            part[((size_t)(t - 1) * PJ + js) * NB + bA0 + lane] = s;
        }
        if (t > 0) {   // phase 2: h partials
            const float* hb = &h_sw[bp * XLD + kc * 36];
            #pragma unroll
            for (int mi = 0; mi < 8; ++mi) {
                float4 hv4 = *(const float4*)(hb + mi * 4);
                #pragma unroll
                for (int i = 0; i < 2; ++i) {
                    float4 w = whh_r[i * 8 + mi];
                    acc[i].x += w.x * hv4.x; acc[i].y += w.y * hv4.y;
                    acc[i].z += w.z * hv4.z; acc[i].w += w.w * hv4.w;
                }
            }
        }
        {   // horizontal add -> red_s (A region, transposed layout)
            float vx = (acc[0].x + acc[0].y) + (acc[0].z + acc[0].w);
            float vy = (acc[1].x + acc[1].y) + (acc[1].z + acc[1].w);
            red_s[kc * RS1 + bp * RS2 + p0]     = vx;
            red_s[kc * RS1 + bp * RS2 + p0 + 4] = vy;
        }
        if (pf && wv < 2) {   // stage x_A(t+1)
            *(f32x4*)(&x_sw[wv * XLD + sphys]) = xst;
        }
        __syncthreads();   // B2a: red_A ready; x_A staged

        if (wv == 0 && lane < 32) {   // epilogue A + publish (b128 reduce)
            float sg0 = bias_g[0], sg1 = bias_g[1], sg2 = bias_g[2], sg3 = bias_g[3];
            #pragma unroll
            for (int k2 = 0; k2 < 8; ++k2) {
                f32x4 rv = *(const f32x4*)(&red_s[k2 * RS1 + eb * RS2 + ejj * 4]);
                sg0 += rv.x; sg1 += rv.y; sg2 += rv.z; sg3 += rv.w;
            }
            float cn = sigf(sg1) * c_reg + sigf(sg0) * tanhf(sg2);
            float hn = sigf(sg3) * tanhf(cn);
            c_reg = cn;
            p_s[lane] = hn * wz_r;
            __hip_atomic_store(
                hbuf + (parOut + bA0 + eb) * HH + j0 + ejj,
                packh((unsigned)(t + 1), hn),
                __ATOMIC_RELAXED, __HIP_MEMORY_SCOPE_AGENT);
        }

        // ================= B half =================
        acc[0] = make_float4(0.f, 0.f, 0.f, 0.f);
        acc[1] = make_float4(0.f, 0.f, 0.f, 0.f);
        {   // phase 1: x partials
            const float* xb = &x_sw[(2 + bp) * XLD + kc * 36];
            #pragma unroll
            for (int mi = 0; mi < 8; ++mi) {
                float4 xv4 = *(const float4*)(xb + mi * 4);
                #pragma unroll
                for (int i = 0; i < 2; ++i) {
                    float4 w = wih_r[i * 8 + mi];
                    acc[i].x += w.x * xv4.x; acc[i].y += w.y * xv4.y;
                    acc[i].z += w.z * xv4.z; acc[i].w += w.w * xv4.w;
                }
            }
        }
        if (t > 0 && inB) {   // B-check (loads long in flight)
            while ((unsigned)(b0v >> 32) != want)
                b0v = __hip_atomic_load(hpB + 0, __ATOMIC_RELAXED, __HIP_MEMORY_SCOPE_AGENT);
            while ((unsigned)(b1v >> 32) != want)
                b1v = __hip_atomic_load(hpB + 1, __ATOMIC_RELAXED, __HIP_MEMORY_SCOPE_AGENT);
            union { unsigned u; float f; } c0, c1;
            c0.u = (unsigned)b0v; c1.u = (unsigned)b1v;
            *(float2*)(&h_sw[(2 + bcb) * XLD + bcph]) = make_float2(c0.f, c1.f);
        }
        __syncthreads();   // B1b: h_B ready; x_B(t) reads done

        if (t > 0 && wv == 3 && lane < 2) {   // part B(t-1)
            float s = 0.f;
            #pragma unroll
            for (int jj = 0; jj < 16; ++jj) s += p_s[32 + lane * 16 + jj];
            part[((size_t)(t - 1) * PJ + js) * NB + bB0 + lane] = s;
        }
        if (t > 0) {   // phase 2: h partials
            const float* hb = &h_sw[(2 + bp) * XLD + kc * 36];
            #pragma unroll
            for (int mi = 0; mi < 8; ++mi) {
                float4 hv4 = *(const float4*)(hb + mi * 4);
                #pragma unroll
                for (int i = 0; i < 2; ++i) {
                    float4 w = whh_r[i * 8 + mi];
                    acc[i].x += w.x * hv4.x; acc[i].y += w.y * hv4.y;
                    acc[i].z += w.z * hv4.z; acc[i].w += w.w * hv4.w;
                }
            }
        }
        {   // horizontal add -> red_s (B region, transposed layout)
            float vx = (acc[0].x + acc[0].y) + (acc[0].z + acc[0].w);
            float vy = (acc[1].x + acc[1].y) + (acc[1].z + acc[1].w);
            red_s[RBOFF + kc * RS1 + bp * RS2 + p0]     = vx;
            red_s[RBOFF + kc * RS1 + bp * RS2 + p0 + 4] = vy;
        }
        if (pf && (wv == 2 || wv == 3)) {   // stage x_B(t+1)
            *(f32x4*)(&x_sw[wv * XLD + sphys]) = xst;
        }
        __syncthreads();   // B2b: red_B ready; x_B staged

        if (wv == 1 && lane < 32) {   // epilogue B + publish
            float sg0 = bias_g[0], sg1 = bias_g[1], sg2 = bias_g[2], sg3 = bias_g[3];
            #pragma unroll
            for (int k2 = 0; k2 < 8; ++k2) {
                f32x4 rv = *(const f32x4*)(&red_s[RBOFF + k2 * RS1 + eb * RS2 + ejj * 4]);
                sg0 += rv.x; sg1 += rv.y; sg2 += rv.z; sg3 += rv.w;
            }
            float cn = sigf(sg1) * c_reg + sigf(sg0) * tanhf(sg2);
            float hn = sigf(sg3) * tanhf(cn);
            c_reg = cn;
            p_s[32 + lane] = hn * wz_r;
            __hip_atomic_store(
                hbuf + (parOut + bB0 + eb) * HH + j0 + ejj,
                packh((unsigned)(t + 1), hn),
                __ATOMIC_RELAXED, __HIP_MEMORY_SCOPE_AGENT);
        }
    }

    // final part-sums (t = TT-1)
    __syncthreads();
    if (wv == 2 && lane < 2) {
        float s = 0.f;
        #pragma unroll
        for (int jj = 0; jj < 16; ++jj) s += p_s[lane * 16 + jj];
        part[((size_t)(TT - 1) * PJ + js) * NB + bA0 + lane] = s;
    }
    if (wv == 3 && lane < 2) {
        float s = 0.f;
        #pragma unroll
        for (int jj = 0; jj < 16; ++jj) s += p_s[32 + lane * 16 + jj];
        part[((size_t)(TT - 1) * PJ + js) * NB + bB0 + lane] = s;
    }
}

__global__ void pz_kernel(const float* __restrict__ part,
                          const float* __restrict__ noise,
                          const float* __restrict__ b_z,
                          float* __restrict__ out)
{
    int idx = blockIdx.x * blockDim.x + threadIdx.x;  // t*64 + b
    if (idx >= TT * NB) return;
    int t = idx >> 6, b = idx & 63;
    float s = b_z[0];
    #pragma unroll
    for (int jg = 0; jg < PJ; ++jg) s += part[(t * PJ + jg) * NB + b];
    float pz = 1.f / (1.f + expf(-s));
    out[idx] = pz;
    out[TT * NB + idx] = (noise[idx] < pz) ? 1.f : 0.f;
}

// One block per batch column: stable compaction of tokens where z==1.
__global__ void compact_kernel(const int* __restrict__ sent,
                               const float* __restrict__ zbuf,
                               float* __restrict__ rat,
                               float* __restrict__ zsz)
{
    __shared__ float rat_s[TT];
    __shared__ int scan_s[256];
    int b = blockIdx.x, tid = threadIdx.x;
    int zloc[8];
    int base = tid * 8;
    int c = 0;
    #pragma unroll
    for (int i = 0; i < 8; ++i) {
        zloc[i] = (zbuf[(base + i) * NB + b] != 0.f) ? 1 : 0;
        c += zloc[i];
    }
    scan_s[tid] = c;
    for (int i = tid; i < TT; i += 256) rat_s[i] = 0.f;
    __syncthreads();
    for (int off = 1; off < 256; off <<= 1) {
        int v = scan_s[tid];
        int add = (tid >= off) ? scan_s[tid - off] : 0;
        __syncthreads();
        scan_s[tid] = v + add;
        __syncthreads();
    }
    int total = scan_s[255];
    int pos = scan_s[tid] - c;  // exclusive prefix
    #pragma unroll
    for (int i = 0; i < 8; ++i) {
        if (zloc[i]) { rat_s[pos] = (float)sent[(base + i) * NB + b]; ++pos; }
    }
    __syncthreads();
    for (int i = tid; i < TT; i += 256) rat[i * NB + b] = rat_s[i];
    if (tid == 0) zsz[b] = (float)total;
}

extern "C" void kernel_launch(void* const* d_in, const int* in_sizes, int n_in,
                              void* d_out, int out_size, void* d_ws, size_t ws_size,
                              hipStream_t stream)
{
    const int*   sent  = (const int*)d_in[0];
    const float* noise = (const float*)d_in[1];
    const float* emb   = (const float*)d_in[2];
    const float* W_ih  = (const float*)d_in[3];
    const float* W_hh  = (const float*)d_in[4];
    const float* b_ih  = (const float*)d_in[5];
    const float* b_hh  = (const float*)d_in[6];
    const float* W_z   = (const float*)d_in[7];
    const float* b_z   = (const float*)d_in[8];
    float* out = (float*)d_out;

    char* ws = (char*)d_ws;
    unsigned long long* hbuf = (unsigned long long*)ws;     // 2*64*256*8 = 256 KB
    float* part = (float*)(ws + 262144);                    // 2048*16*64*4 = 8 MB

    // tags must start != any expected tag (1..2048)
    (void)hipMemsetAsync(hbuf, 0, 2 * NB * HH * sizeof(unsigned long long), stream);

    // ~27KB static + 64KB dynamic -> ~91KB -> exactly 1 WG/CU
    lstm_kernel<<<256, 512, 65536, stream>>>(sent, emb, W_ih, W_hh, b_ih, b_hh,
                                             W_z, hbuf, part);
    pz_kernel<<<(TT * NB) / 256, 256, 0, stream>>>(part, noise, b_z, out);
    compact_kernel<<<NB, 256, 0, stream>>>(sent, out + TT * NB,
                                           out + 2 * TT * NB, out + 3 * TT * NB);
}